// Round 14
// baseline (187.616 us; speedup 1.0000x reference)
//
#include <hip/hip_runtime.h>

// Problem constants
#define B_    1024
#define C_    128
#define ELL   16
#define EQ    3
#define E_    10
#define P3    23
#define P2    5
#define NSEG  176            // padded segment row: 16 f4-aligned v-segments
#define NI4   44             // NSEG/4
#define RSTR  180            // V3L row stride (180%32=20 -> 2-way bank aliasing, free)
#define KD    28             // folded weight depth: 23 (wmax) + 5 (w2)

// ws layout (bytes)
#define WS_CNT   0
#define WS_LIST  64
#define WS_COEF  65536                 // coefG[48][176][28] = 946 KB
#define WS_S     (2u << 20)            // Sg f4-layout [e][48][44][128] = 43.3 MB

// segment offsets: v-th segment holds [lin_v, Q_vv, Q_v,v+1, .., Q_v,15, pad0s]
// lengths (real) 17-v, padded to x4: {20,16,16,16,16,12,12,12,12,8,8,8,8,4,4,4}
#define SEG_OFF_INIT {0,20,36,52,68,84,96,108,120,132,140,148,156,164,168,172}

// ---------------------------------------------------------------------------
// Bucketing: bucket batch indices by element, pad each bucket to x64 by
// replicating the last real index (k_main then needs no load guards).
__device__ void do_lists(const float* __restrict__ y, int* __restrict__ cnt_g,
                         int* __restrict__ list_g, int t) {
    __shared__ int lcnt[E_];
    if (t < E_) lcnt[t] = 0;
    __syncthreads();
    for (int r = 0; r < 4; ++r) {
        int b = t + 256 * r;
        int e = 0;
        #pragma unroll
        for (int j = 1; j < E_; ++j)
            if (y[b * E_ + j] > 0.5f) e = j;
        int slot = atomicAdd(&lcnt[e], 1);
        list_g[e * B_ + slot] = b;
    }
    __syncthreads();
    if (t < E_) {
        int c0 = lcnt[t];
        cnt_g[t] = c0;
        int last = (c0 > 0) ? list_g[t * B_ + c0 - 1] : 0;
        int cp = (c0 + 63) & ~63;
        if (cp > B_) cp = B_;
        for (int s2 = c0; s2 < cp; ++s2) list_g[t * B_ + s2] = last;
    }
}

// ---------------------------------------------------------------------------
// k_coef: materialize symmetrized coefficient rows (same algebra/ordering as
// r12's verified k_s):
//   t<136 slots (v,l>0): coef[k<23] = U3[j,v,i,k] + (i!=v)*U3[j,i,v,k], i=v+l-1
//   l==0 slots:          coef[23+q] = U2[j,v,q]
//   pad slots: zero.
// coefG[j][t][28], row stride 112 B (16B-aligned for s_load_dwordx4).
// grid 49: blocks 0..47 -> j; block 48 does bucketing.
__global__ __launch_bounds__(256, 2) void k_coef(const float* __restrict__ U3,
                                                 const float* __restrict__ U2,
                                                 const float* __restrict__ y,
                                                 float* __restrict__ coefG,
                                                 int* __restrict__ cnt_g,
                                                 int* __restrict__ list_g) {
    const int t = threadIdx.x;
    if (blockIdx.x == 48) { do_lists(y, cnt_g, list_g, t); return; }
    __shared__ __align__(16) float U3L[ELL * ELL * P3];  // 23,552 B
    const int j = blockIdx.x;

    {   // stage U3[j] (1472 f4), fully coalesced
        const float4* src4 = (const float4*)(U3 + (size_t)j * (ELL * ELL * P3));
        float4* dst4 = (float4*)U3L;
        for (int f = t; f < 1472; f += 256) dst4[f] = src4[f];
    }
    __syncthreads();
    if (t >= NSEG) return;

    const int SO[16] = SEG_OFF_INIT;
    int v = 0;
    #pragma unroll
    for (int s = 1; s < 16; ++s) v += (t >= SO[s]) ? 1 : 0;
    const int l    = t - SO[v];
    const int real = 17 - v;

    float outk[KD];
    #pragma unroll
    for (int k = 0; k < KD; ++k) outk[k] = 0.f;

    if (l == 0) {
        #pragma unroll
        for (int q = 0; q < P2; ++q)
            outk[23 + q] = U2[(size_t)j * (ELL * P2) + v * P2 + q];
    } else if (l < real) {
        int i = v + l - 1;
        const float* pa = &U3L[(v * ELL + i) * P3];
        const float* pb = &U3L[(i * ELL + v) * P3];
        if (i != v) {
            #pragma unroll
            for (int k = 0; k < P3; ++k) outk[k] = pa[k] + pb[k];
        } else {
            #pragma unroll
            for (int k = 0; k < P3; ++k) outk[k] = pa[k];
        }
    }
    float* cr = coefG + ((size_t)j * NSEG + t) * KD;
    #pragma unroll
    for (int k = 0; k < KD; ++k) cr[k] = outk[k];
}

// ---------------------------------------------------------------------------
// k_s v2: Sg_f4[((e*48 + j)*44 + i4)*128 + c] = {s_{4i4..4i4+3}} where
//   s_idx = sum_k coefG[j][idx][k] * wl[k],  wl = {wmax[e,*,c], w2[e,*,c]}.
// lane = c (wl in VGPRs, coalesced loads); coef row addresses are wave-
// uniform (loop var only) -> scalar s_load broadcasts, ZERO LDS. Stores:
// float4 (4 idx packed), lanes stride 16B -> perfectly coalesced.
// grid (48, E), 256 threads: c = t&127, half = t>>7 splits the i4 range.
__global__ __launch_bounds__(256, 4) void k_s(const float* __restrict__ coefG,
                                              const float* __restrict__ wmax,
                                              const float* __restrict__ w2,
                                              float4* __restrict__ Sg4) {
    const int t = threadIdx.x;
    const int j = blockIdx.x, e = blockIdx.y;
    const int c = t & 127, half = t >> 7;

    float wl[KD];
    #pragma unroll
    for (int k = 0; k < P3; ++k) wl[k] = wmax[(e * P3 + k) * C_ + c];
    #pragma unroll
    for (int q = 0; q < P2; ++q) wl[23 + q] = w2[(e * P2 + q) * C_ + c];

    const float* cb = coefG + (size_t)j * NSEG * KD;
    float4* dst = Sg4 + (size_t)(e * 48 + j) * NI4 * 128 + c;

    const int i4lo = half * 22, i4hi = i4lo + 22;
    #pragma clang loop unroll(disable)
    for (int i4 = i4lo; i4 < i4hi; ++i4) {
        float s[4];
        #pragma unroll
        for (int l = 0; l < 4; ++l) {
            const float* cr = cb + (size_t)(4 * i4 + l) * KD;   // wave-uniform
            float a = 0.f;
            #pragma unroll
            for (int k = 0; k < KD; ++k) a += cr[k] * wl[k];
            s[l] = a;
        }
        float4 o; o.x = s[0]; o.y = s[1]; o.z = s[2]; o.w = s[3];
        dst[(size_t)i4 * 128] = o;
    }
}

// ---------------------------------------------------------------------------
// k_main: r12's verified hot loop (46 us), fill adapted to the f4 Sg layout.
// grid (C_*EQ, E_), 256 threads; bx = c*3+w. xx = t&15 (row), bs = t>>4;
// 4 batch rows/thread -> chunk = 64 rows.
// CRITICAL: __syncthreads() per chunk + unroll(disable) -- without them LICM
// hoists loop-invariant LDS reads -> VGPR blowup -> scratch spill (r5/r6).
// (r13 lesson: 8 rows/thread @128thr -> VGPR 112, occupancy 19%, regression.)
__global__ __launch_bounds__(256, 2) void k_main(
    const float* __restrict__ x, const float4* __restrict__ Sg4,
    const float* __restrict__ U1, const float* __restrict__ w1,
    const int* __restrict__ cnt_g, const int* __restrict__ list_g,
    float* __restrict__ out) {

    __shared__ __align__(16) float V3L[16 * RSTR];   // 11,520 B

    const int t  = threadIdx.x;
    const int bx = blockIdx.x;
    const int w  = bx % 3, c = bx / 3;
    const int e  = blockIdx.y;
    const int xx = t & 15, bs = t >> 4;
    const int cnt  = cnt_g[e];
    const int cntp = (cnt + 63) & ~63;

    // ---- fill V3L: rows w*16..w*16+15, 44 f4 each. src f4 idx = f*128 + c
    // (f = row*44+i4 relative to row w*16) -- scattered 16B reads, L2/L3-hot.
    {
        const float4* src = Sg4 + (size_t)(e * 48 + w * 16) * NI4 * 128 + c;
        #pragma unroll
        for (int rr = 0; rr < 3; ++rr) {
            int f = t + 256 * rr;
            if (f < 704) {
                float4 u = src[(size_t)f * 128];
                int row = f / NI4, i4 = f - row * NI4;
                *(float4*)(&V3L[row * RSTR + 4 * i4]) = u;
            }
        }
    }
    const float v1x = U1[w * 16 + xx] * w1[e * C_ + c];
    __syncthreads();

    const float* v3p = &V3L[xx * RSTR];
    const int SO[16] = SEG_OFF_INIT;

    // ---- chunk loop: 64 rows per chunk, 4 per thread ----
    #pragma clang loop unroll(disable)
    for (int base = 0; base < cntp; base += 64) {
        __syncthreads();   // anti-LICM liveness pin (see header note)

        const int slot = base + bs * 4;
        int bidx[4];
        #pragma unroll
        for (int r = 0; r < 4; ++r) bidx[r] = list_g[e * B_ + slot + r];

        float xm[4][19];   // x row + 3 zero pads (segment tails index up to 18)
        float xo[4];
        #pragma unroll
        for (int r = 0; r < 4; ++r) {
            const float* xb = x + ((size_t)bidx[r] * C_ + c) * ELL;
            #pragma unroll
            for (int i4 = 0; i4 < 4; ++i4) {
                float4 a = ((const float4*)xb)[i4];
                xm[r][4 * i4 + 0] = a.x; xm[r][4 * i4 + 1] = a.y;
                xm[r][4 * i4 + 2] = a.z; xm[r][4 * i4 + 3] = a.w;
            }
            xm[r][16] = 0.f; xm[r][17] = 0.f; xm[r][18] = 0.f;
            xo[r] = xb[xx];   // own-x element (L1 hit; no dynamic reg index)
        }

        float t2[4] = {0.f, 0.f, 0.f, 0.f};
        #pragma unroll
        for (int v = 0; v < 16; ++v) {
            const int off = SO[v];
            const int nf4 = (v == 0) ? 5 : (v < 5) ? 4 : (v < 9) ? 3 : (v < 13) ? 2 : 1;
            float inner[4];
            {   // first f4: [lin, Q_vv, Q_v,v+1, Q_v,v+2]
                float4 u = *(const float4*)(v3p + off);
                #pragma unroll
                for (int r = 0; r < 4; ++r)
                    inner[r] = u.x + u.y * xm[r][v]
                             + u.z * xm[r][v + 1] + u.w * xm[r][v + 2];
            }
            #pragma unroll
            for (int q = 1; q < nf4; ++q) {
                float4 u = *(const float4*)(v3p + off + 4 * q);
                #pragma unroll
                for (int r = 0; r < 4; ++r) {
                    inner[r] += u.x * xm[r][v + 4 * q - 1];
                    inner[r] += u.y * xm[r][v + 4 * q + 0];
                    inner[r] += u.z * xm[r][v + 4 * q + 1];
                    inner[r] += u.w * xm[r][v + 4 * q + 2];
                }
            }
            #pragma unroll
            for (int r = 0; r < 4; ++r) t2[r] += xm[r][v] * inner[r];
        }

        // out[b,c,w] = sum_xx (t2 + v1[xx]) * x[xx]  -- width-16 butterfly
        float cv[4];
        #pragma unroll
        for (int r = 0; r < 4; ++r) cv[r] = (t2[r] + v1x) * xo[r];
        #pragma unroll
        for (int m = 1; m < 16; m <<= 1) {
            #pragma unroll
            for (int r = 0; r < 4; ++r) cv[r] += __shfl_xor(cv[r], m, 16);
        }
        if (xx == 0) {
            #pragma unroll
            for (int r = 0; r < 4; ++r)
                if (slot + r < cnt)
                    out[(size_t)bidx[r] * (C_ * EQ) + c * EQ + w] = cv[r];
        }
    }
}

// ---------------------------------------------------------------------------
extern "C" void kernel_launch(void* const* d_in, const int* in_sizes, int n_in,
                              void* d_out, int out_size, void* d_ws, size_t ws_size,
                              hipStream_t stream) {
    const float* x    = (const float*)d_in[0];
    const float* y    = (const float*)d_in[1];
    const float* U3   = (const float*)d_in[2];
    const float* U2   = (const float*)d_in[3];
    const float* U1   = (const float*)d_in[4];
    const float* wmax = (const float*)d_in[5];
    const float* w2   = (const float*)d_in[6];
    const float* w1   = (const float*)d_in[7];
    float* out = (float*)d_out;
    char*  ws  = (char*)d_ws;

    int*    cnt_g  = (int*)(ws + WS_CNT);
    int*    list_g = (int*)(ws + WS_LIST);
    float*  coefG  = (float*)(ws + WS_COEF);
    float4* Sg4    = (float4*)(ws + WS_S);
    (void)ws_size;   // needs ~45.3 MB; harness ws confirmed >= 66 MB (r1-r9)

    k_coef<<<49, 256, 0, stream>>>(U3, U2, y, coefG, cnt_g, list_g);
    k_s<<<dim3(48, E_), 256, 0, stream>>>(coefG, wmax, w2, Sg4);
    k_main<<<dim3(C_ * EQ, E_), 256, 0, stream>>>(x, Sg4, U1, w1, cnt_g, list_g, out);
}

// Round 15
// 163.209 us; speedup vs baseline: 1.1495x; 1.1495x over previous
//
#include <hip/hip_runtime.h>

// Problem constants
#define B_    1024
#define C_    128
#define ELL   16
#define EQ    3
#define E_    10
#define P3    23
#define P2    5
#define NSEG  176            // padded segment row: 16 f4-aligned v-segments
#define NI4   44             // NSEG/4
#define RSTR  180            // row stride (180%32=20 -> 2-way bank aliasing, free)
#define SRS   (48 * RSTR)    // 8640 floats per (e,c) S-slice
#define KD    28             // folded weight depth: 23 (wmax) + 5 (w2)

// ws layout (bytes)
#define WS_CNT   0
#define WS_LIST  64
#define WS_COEF  65536                 // coefG[48][176][28] = 946 KB
#define WS_S     (2u << 20)            // Sg r12 layout [e][c][48*RSTR] = 44.2 MB

// segment offsets: v-th segment holds [lin_v, Q_vv, Q_v,v+1, .., Q_v,15, pad0s]
// lengths (real) 17-v, padded to x4: {20,16,16,16,16,12,12,12,12,8,8,8,8,4,4,4}
#define SEG_OFF_INIT {0,20,36,52,68,84,96,108,120,132,140,148,156,164,168,172}

// ---------------------------------------------------------------------------
// Bucketing: bucket batch indices by element, pad each bucket to x64 by
// replicating the last real index (k_main then needs no load guards).
__device__ void do_lists(const float* __restrict__ y, int* __restrict__ cnt_g,
                         int* __restrict__ list_g, int t) {
    __shared__ int lcnt[E_];
    if (t < E_) lcnt[t] = 0;
    __syncthreads();
    for (int r = 0; r < 4; ++r) {
        int b = t + 256 * r;
        int e = 0;
        #pragma unroll
        for (int j = 1; j < E_; ++j)
            if (y[b * E_ + j] > 0.5f) e = j;
        int slot = atomicAdd(&lcnt[e], 1);
        list_g[e * B_ + slot] = b;
    }
    __syncthreads();
    if (t < E_) {
        int c0 = lcnt[t];
        cnt_g[t] = c0;
        int last = (c0 > 0) ? list_g[t * B_ + c0 - 1] : 0;
        int cp = (c0 + 63) & ~63;
        if (cp > B_) cp = B_;
        for (int s2 = c0; s2 < cp; ++s2) list_g[t * B_ + s2] = last;
    }
}

// ---------------------------------------------------------------------------
// k_coef: materialize symmetrized coefficient rows (verified in r14):
//   t<136 slots (v,l>0): coef[k<23] = U3[j,v,i,k] + (i!=v)*U3[j,i,v,k], i=v+l-1
//   l==0 slots:          coef[23+q] = U2[j,v,q]; pad slots zero.
// coefG[j][t][28], 112 B rows (16B-aligned for s_load_dwordx4).
// grid 49: blocks 0..47 -> j; block 48 does bucketing.
__global__ __launch_bounds__(256, 2) void k_coef(const float* __restrict__ U3,
                                                 const float* __restrict__ U2,
                                                 const float* __restrict__ y,
                                                 float* __restrict__ coefG,
                                                 int* __restrict__ cnt_g,
                                                 int* __restrict__ list_g) {
    const int t = threadIdx.x;
    if (blockIdx.x == 48) { do_lists(y, cnt_g, list_g, t); return; }
    __shared__ __align__(16) float U3L[ELL * ELL * P3];  // 23,552 B
    const int j = blockIdx.x;

    {   // stage U3[j] (1472 f4), fully coalesced
        const float4* src4 = (const float4*)(U3 + (size_t)j * (ELL * ELL * P3));
        float4* dst4 = (float4*)U3L;
        for (int f = t; f < 1472; f += 256) dst4[f] = src4[f];
    }
    __syncthreads();
    if (t >= NSEG) return;

    const int SO[16] = SEG_OFF_INIT;
    int v = 0;
    #pragma unroll
    for (int s = 1; s < 16; ++s) v += (t >= SO[s]) ? 1 : 0;
    const int l    = t - SO[v];
    const int real = 17 - v;

    float outk[KD];
    #pragma unroll
    for (int k = 0; k < KD; ++k) outk[k] = 0.f;

    if (l == 0) {
        #pragma unroll
        for (int q = 0; q < P2; ++q)
            outk[23 + q] = U2[(size_t)j * (ELL * P2) + v * P2 + q];
    } else if (l < real) {
        int i = v + l - 1;
        const float* pa = &U3L[(v * ELL + i) * P3];
        const float* pb = &U3L[(i * ELL + v) * P3];
        if (i != v) {
            #pragma unroll
            for (int k = 0; k < P3; ++k) outk[k] = pa[k] + pb[k];
        } else {
            #pragma unroll
            for (int k = 0; k < P3; ++k) outk[k] = pa[k];
        }
    }
    float* cr = coefG + ((size_t)j * NSEG + t) * KD;
    #pragma unroll
    for (int k = 0; k < KD; ++k) cr[k] = outk[k];
}

// ---------------------------------------------------------------------------
// k_s: scalar-pipe GEMM-let, storing DIRECTLY into r12's Sg layout.
//   Sg[(e*C+c)*SRS + j*RSTR + idx] = sum_k coefG[j][idx][k] * wl[k],
//   wl = {wmax[e,*,c], w2[e,*,c]} in VGPRs (lane = c, coalesced loads).
// coef rows at wave-uniform addresses -> s_load broadcasts (SMEM pipe, zero
// LDS -- r12's k_s paid 7 LDS-broadcast b128 per output, the structural cost
// this removes). Stores: f4 per lane, SRS-stride scatter per instruction, but
// each lane's stream is contiguous over i4 -> L2 merges to full lines.
// grid (48, E, 2), 256 thr: c = t&127; range = z*2 + (t>>7) picks 11 of 44 i4.
// (r14 lesson: 480-block version = 3.75 waves/CU, latency-bound; now 15/CU.)
__global__ __launch_bounds__(256, 4) void k_s(const float* __restrict__ coefG,
                                              const float* __restrict__ wmax,
                                              const float* __restrict__ w2,
                                              float* __restrict__ Sg) {
    const int t = threadIdx.x;
    const int j = blockIdx.x, e = blockIdx.y;
    const int c = t & 127;
    const int rg = blockIdx.z * 2 + (t >> 7);   // wave-uniform range id

    float wl[KD];
    #pragma unroll
    for (int k = 0; k < P3; ++k) wl[k] = wmax[(e * P3 + k) * C_ + c];
    #pragma unroll
    for (int q = 0; q < P2; ++q) wl[23 + q] = w2[(e * P2 + q) * C_ + c];

    const float* cb = coefG + (size_t)j * NSEG * KD;
    float* dst = Sg + (size_t)(e * C_ + c) * SRS + j * RSTR;

    const int i4lo = rg * 11, i4hi = i4lo + 11;
    #pragma clang loop unroll(disable)
    for (int i4 = i4lo; i4 < i4hi; ++i4) {
        float s[4];
        #pragma unroll
        for (int l = 0; l < 4; ++l) {
            const float* cr = cb + (size_t)(4 * i4 + l) * KD;   // wave-uniform
            float a = 0.f;
            #pragma unroll
            for (int k = 0; k < KD; ++k) a += cr[k] * wl[k];
            s[l] = a;
        }
        float4 o; o.x = s[0]; o.y = s[1]; o.z = s[2]; o.w = s[3];
        *(float4*)(dst + 4 * i4) = o;
    }
}

// ---------------------------------------------------------------------------
// k_main: EXACT r12 hot loop + fill (verified 46 us, FETCH 46 MB).
// grid (C_*EQ, E_), 256 threads; bx = c*3+w. xx = t&15 (row), bs = t>>4;
// 4 batch rows/thread -> chunk = 64 rows.
// CRITICAL: __syncthreads() per chunk + unroll(disable) -- without them LICM
// hoists loop-invariant LDS reads -> VGPR blowup -> scratch spill (r5/r6).
// (r13 lesson: 8 rows/thread -> VGPR 112, occupancy 19%, regression.
//  r14 lesson: strided Sg layout -> fill gather -> FETCH 194 MB, +34 us.)
__global__ __launch_bounds__(256, 2) void k_main(
    const float* __restrict__ x, const float* __restrict__ Sg,
    const float* __restrict__ U1, const float* __restrict__ w1,
    const int* __restrict__ cnt_g, const int* __restrict__ list_g,
    float* __restrict__ out) {

    __shared__ __align__(16) float V3L[16 * RSTR];   // 11,520 B

    const int t  = threadIdx.x;
    const int bx = blockIdx.x;
    const int w  = bx % 3, c = bx / 3;
    const int e  = blockIdx.y;
    const int xx = t & 15, bs = t >> 4;
    const int cnt  = cnt_g[e];
    const int cntp = (cnt + 63) & ~63;

    // ---- fill V3L: this w's 16 rows = 2880 floats = 720 f4, straight copy
    {
        const float4* src = (const float4*)(Sg + (size_t)(e * C_ + c) * SRS
                                            + (size_t)w * 16 * RSTR);
        float4* dst = (float4*)V3L;
        #pragma unroll
        for (int r = 0; r < 2; ++r) dst[t + 256 * r] = src[t + 256 * r];
        if (t < 208) dst[512 + t] = src[512 + t];
    }
    const float v1x = U1[w * 16 + xx] * w1[e * C_ + c];
    __syncthreads();

    const float* v3p = &V3L[xx * RSTR];
    const int SO[16] = SEG_OFF_INIT;

    // ---- chunk loop: 64 rows per chunk, 4 per thread ----
    #pragma clang loop unroll(disable)
    for (int base = 0; base < cntp; base += 64) {
        __syncthreads();   // anti-LICM liveness pin (see header note)

        const int slot = base + bs * 4;
        int bidx[4];
        #pragma unroll
        for (int r = 0; r < 4; ++r) bidx[r] = list_g[e * B_ + slot + r];

        float xm[4][19];   // x row + 3 zero pads (segment tails index up to 18)
        float xo[4];
        #pragma unroll
        for (int r = 0; r < 4; ++r) {
            const float* xb = x + ((size_t)bidx[r] * C_ + c) * ELL;
            #pragma unroll
            for (int i4 = 0; i4 < 4; ++i4) {
                float4 a = ((const float4*)xb)[i4];
                xm[r][4 * i4 + 0] = a.x; xm[r][4 * i4 + 1] = a.y;
                xm[r][4 * i4 + 2] = a.z; xm[r][4 * i4 + 3] = a.w;
            }
            xm[r][16] = 0.f; xm[r][17] = 0.f; xm[r][18] = 0.f;
            xo[r] = xb[xx];   // own-x element (L1 hit; no dynamic reg index)
        }

        float t2[4] = {0.f, 0.f, 0.f, 0.f};
        #pragma unroll
        for (int v = 0; v < 16; ++v) {
            const int off = SO[v];
            const int nf4 = (v == 0) ? 5 : (v < 5) ? 4 : (v < 9) ? 3 : (v < 13) ? 2 : 1;
            float inner[4];
            {   // first f4: [lin, Q_vv, Q_v,v+1, Q_v,v+2]
                float4 u = *(const float4*)(v3p + off);
                #pragma unroll
                for (int r = 0; r < 4; ++r)
                    inner[r] = u.x + u.y * xm[r][v]
                             + u.z * xm[r][v + 1] + u.w * xm[r][v + 2];
            }
            #pragma unroll
            for (int q = 1; q < nf4; ++q) {
                float4 u = *(const float4*)(v3p + off + 4 * q);
                #pragma unroll
                for (int r = 0; r < 4; ++r) {
                    inner[r] += u.x * xm[r][v + 4 * q - 1];
                    inner[r] += u.y * xm[r][v + 4 * q + 0];
                    inner[r] += u.z * xm[r][v + 4 * q + 1];
                    inner[r] += u.w * xm[r][v + 4 * q + 2];
                }
            }
            #pragma unroll
            for (int r = 0; r < 4; ++r) t2[r] += xm[r][v] * inner[r];
        }

        // out[b,c,w] = sum_xx (t2 + v1[xx]) * x[xx]  -- width-16 butterfly
        float cv[4];
        #pragma unroll
        for (int r = 0; r < 4; ++r) cv[r] = (t2[r] + v1x) * xo[r];
        #pragma unroll
        for (int m = 1; m < 16; m <<= 1) {
            #pragma unroll
            for (int r = 0; r < 4; ++r) cv[r] += __shfl_xor(cv[r], m, 16);
        }
        if (xx == 0) {
            #pragma unroll
            for (int r = 0; r < 4; ++r)
                if (slot + r < cnt)
                    out[(size_t)bidx[r] * (C_ * EQ) + c * EQ + w] = cv[r];
        }
    }
}

// ---------------------------------------------------------------------------
extern "C" void kernel_launch(void* const* d_in, const int* in_sizes, int n_in,
                              void* d_out, int out_size, void* d_ws, size_t ws_size,
                              hipStream_t stream) {
    const float* x    = (const float*)d_in[0];
    const float* y    = (const float*)d_in[1];
    const float* U3   = (const float*)d_in[2];
    const float* U2   = (const float*)d_in[3];
    const float* U1   = (const float*)d_in[4];
    const float* wmax = (const float*)d_in[5];
    const float* w2   = (const float*)d_in[6];
    const float* w1   = (const float*)d_in[7];
    float* out = (float*)d_out;
    char*  ws  = (char*)d_ws;

    int*   cnt_g  = (int*)(ws + WS_CNT);
    int*   list_g = (int*)(ws + WS_LIST);
    float* coefG  = (float*)(ws + WS_COEF);
    float* Sg     = (float*)(ws + WS_S);
    (void)ws_size;   // needs ~46.3 MB; harness ws confirmed >= 66 MB (r1-r9)

    k_coef<<<49, 256, 0, stream>>>(U3, U2, y, coefG, cnt_g, list_g);
    k_s<<<dim3(48, E_, 2), 256, 0, stream>>>(coefG, wmax, w2, Sg);
    k_main<<<dim3(C_ * EQ, E_), 256, 0, stream>>>(x, Sg, U1, w1, cnt_g, list_g, out);
}

// Round 16
// 154.900 us; speedup vs baseline: 1.2112x; 1.0536x over previous
//
#include <hip/hip_runtime.h>

// Problem constants
#define B_    1024
#define C_    128
#define ELL   16
#define EQ    3
#define E_    10
#define P3    23
#define P2    5
#define NSEG  176            // padded segment row: 16 f4-aligned v-segments
#define NI4   44             // NSEG/4
#define RSTR  180            // row stride (180%32=20 -> 2-way bank aliasing, free)
#define SRS   (48 * RSTR)    // 8640 floats per (e,c) S-slice
#define KD    28             // folded weight depth: 23 (wmax) + 5 (w2)
#define TSTR  129            // k_s transpose-tile row stride (bank=(idx+c)%32)

// ws layout (bytes)
#define WS_CNT   0
#define WS_LIST  64
#define WS_COEF  65536                 // coefG[48][176][28] = 946 KB
#define WS_S     (2u << 20)            // Sg r12 layout [e][c][48*RSTR] = 44.2 MB

// segment offsets: v-th segment holds [lin_v, Q_vv, Q_v,v+1, .., Q_v,15, pad0s]
// lengths (real) 17-v, padded to x4: {20,16,16,16,16,12,12,12,12,8,8,8,8,4,4,4}
#define SEG_OFF_INIT {0,20,36,52,68,84,96,108,120,132,140,148,156,164,168,172}

// ---------------------------------------------------------------------------
// Bucketing: bucket batch indices by element, pad each bucket to x64 by
// replicating the last real index (k_main then needs no load guards).
__device__ void do_lists(const float* __restrict__ y, int* __restrict__ cnt_g,
                         int* __restrict__ list_g, int t) {
    __shared__ int lcnt[E_];
    if (t < E_) lcnt[t] = 0;
    __syncthreads();
    for (int r = 0; r < 4; ++r) {
        int b = t + 256 * r;
        int e = 0;
        #pragma unroll
        for (int j = 1; j < E_; ++j)
            if (y[b * E_ + j] > 0.5f) e = j;
        int slot = atomicAdd(&lcnt[e], 1);
        list_g[e * B_ + slot] = b;
    }
    __syncthreads();
    if (t < E_) {
        int c0 = lcnt[t];
        cnt_g[t] = c0;
        int last = (c0 > 0) ? list_g[t * B_ + c0 - 1] : 0;
        int cp = (c0 + 63) & ~63;
        if (cp > B_) cp = B_;
        for (int s2 = c0; s2 < cp; ++s2) list_g[t * B_ + s2] = last;
    }
}

// ---------------------------------------------------------------------------
// k_coef: materialize symmetrized coefficient rows (verified r14/r15):
//   t<136 slots (v,l>0): coef[k<23] = U3[j,v,i,k] + (i!=v)*U3[j,i,v,k], i=v+l-1
//   l==0 slots:          coef[23+q] = U2[j,v,q]; pad slots zero.
// coefG[j][t][28], 112 B rows. grid 49: blocks 0..47 -> j; block 48 buckets.
__global__ __launch_bounds__(256, 2) void k_coef(const float* __restrict__ U3,
                                                 const float* __restrict__ U2,
                                                 const float* __restrict__ y,
                                                 float* __restrict__ coefG,
                                                 int* __restrict__ cnt_g,
                                                 int* __restrict__ list_g) {
    const int t = threadIdx.x;
    if (blockIdx.x == 48) { do_lists(y, cnt_g, list_g, t); return; }
    __shared__ __align__(16) float U3L[ELL * ELL * P3];  // 23,552 B
    const int j = blockIdx.x;

    {   // stage U3[j] (1472 f4), fully coalesced
        const float4* src4 = (const float4*)(U3 + (size_t)j * (ELL * ELL * P3));
        float4* dst4 = (float4*)U3L;
        for (int f = t; f < 1472; f += 256) dst4[f] = src4[f];
    }
    __syncthreads();
    if (t >= NSEG) return;

    const int SO[16] = SEG_OFF_INIT;
    int v = 0;
    #pragma unroll
    for (int s = 1; s < 16; ++s) v += (t >= SO[s]) ? 1 : 0;
    const int l    = t - SO[v];
    const int real = 17 - v;

    float outk[KD];
    #pragma unroll
    for (int k = 0; k < KD; ++k) outk[k] = 0.f;

    if (l == 0) {
        #pragma unroll
        for (int q = 0; q < P2; ++q)
            outk[23 + q] = U2[(size_t)j * (ELL * P2) + v * P2 + q];
    } else if (l < real) {
        int i = v + l - 1;
        const float* pa = &U3L[(v * ELL + i) * P3];
        const float* pb = &U3L[(i * ELL + v) * P3];
        if (i != v) {
            #pragma unroll
            for (int k = 0; k < P3; ++k) outk[k] = pa[k] + pb[k];
        } else {
            #pragma unroll
            for (int k = 0; k < P3; ++k) outk[k] = pa[k];
        }
    }
    float* cr = coefG + ((size_t)j * NSEG + t) * KD;
    #pragma unroll
    for (int k = 0; k < KD; ++k) cr[k] = outk[k];
}

// ---------------------------------------------------------------------------
// k_s v3: scalar-pipe compute (r15, VALUBusy proved it cheap) + LDS transpose
// so global stores are COALESCED (r15's lane=c direct store scattered 64
// lanes x 34.5KB stride -> WRITE_SIZE 116 MB for 44 MB data, 57 us).
// grid (48, E), 256 threads, 2 passes of 22 i4:
//  compute: c = t&127, h = t>>7 -> 11 i4 each; coef rows at wave-uniform
//           addresses (scalar/broadcast loads, zero LDS); results to
//           T[idxl][c], stride 129 -> compute-writes conflict-free.
//  store:   flat f = t+256s: c2 = f/22, i4l = f%22 -> runs of 22 contiguous
//           f4 (352B) per c2 -> ~17 lines/instr (ideal 16). T reads ~3-way.
__global__ __launch_bounds__(256, 2) void k_s(const float* __restrict__ coefG,
                                              const float* __restrict__ wmax,
                                              const float* __restrict__ w2,
                                              float* __restrict__ Sg) {
    __shared__ float T[88 * TSTR];   // 45,408 B
    const int t = threadIdx.x;
    const int j = blockIdx.x, e = blockIdx.y;
    const int c = t & 127, h = t >> 7;

    float wl[KD];
    #pragma unroll
    for (int k = 0; k < P3; ++k) wl[k] = wmax[(e * P3 + k) * C_ + c];
    #pragma unroll
    for (int q = 0; q < P2; ++q) wl[23 + q] = w2[(e * P2 + q) * C_ + c];

    const float* cb = coefG + (size_t)j * NSEG * KD;

    #pragma clang loop unroll(disable)
    for (int p = 0; p < 2; ++p) {
        const int i4lo = p * 22 + h * 11;
        #pragma clang loop unroll(disable)
        for (int il = 0; il < 11; ++il) {
            const int i4 = i4lo + il;
            float s[4];
            #pragma unroll
            for (int l = 0; l < 4; ++l) {
                const float* cr = cb + (size_t)(4 * i4 + l) * KD;  // wave-uniform
                float a = 0.f;
                #pragma unroll
                for (int k = 0; k < KD; ++k) a += cr[k] * wl[k];
                s[l] = a;
            }
            const int idxl = 4 * i4 - p * 88;   // in [h*44, h*44+44)
            #pragma unroll
            for (int q = 0; q < 4; ++q) T[(idxl + q) * TSTR + c] = s[q];
        }
        __syncthreads();

        // coalesced store of this pass's 88-idx stripe for all 128 c
        #pragma clang loop unroll(disable)
        for (int s2 = 0; s2 < 11; ++s2) {
            const int f = t + 256 * s2;          // 0..2815
            const int c2 = f / 22, i4l = f - c2 * 22;
            float4 o;
            o.x = T[(4 * i4l + 0) * TSTR + c2];
            o.y = T[(4 * i4l + 1) * TSTR + c2];
            o.z = T[(4 * i4l + 2) * TSTR + c2];
            o.w = T[(4 * i4l + 3) * TSTR + c2];
            *(float4*)(Sg + (size_t)(e * C_ + c2) * SRS + j * RSTR
                       + p * 88 + 4 * i4l) = o;
        }
        __syncthreads();
    }
}

// ---------------------------------------------------------------------------
// k_main: EXACT r12 hot loop + fill (verified 46 us, FETCH 46 MB).
// grid (C_*EQ, E_), 256 threads; bx = c*3+w. xx = t&15 (row), bs = t>>4;
// 4 batch rows/thread -> chunk = 64 rows.
// CRITICAL: __syncthreads() per chunk + unroll(disable) -- without them LICM
// hoists loop-invariant LDS reads -> VGPR blowup -> scratch spill (r5/r6).
// (r13: 8 rows/thread -> occupancy 19%, regression. r14: strided Sg layout ->
//  fill gather -> FETCH 194 MB, +34 us. r15: lane=c k_s store scatter, 57 us.)
__global__ __launch_bounds__(256, 2) void k_main(
    const float* __restrict__ x, const float* __restrict__ Sg,
    const float* __restrict__ U1, const float* __restrict__ w1,
    const int* __restrict__ cnt_g, const int* __restrict__ list_g,
    float* __restrict__ out) {

    __shared__ __align__(16) float V3L[16 * RSTR];   // 11,520 B

    const int t  = threadIdx.x;
    const int bx = blockIdx.x;
    const int w  = bx % 3, c = bx / 3;
    const int e  = blockIdx.y;
    const int xx = t & 15, bs = t >> 4;
    const int cnt  = cnt_g[e];
    const int cntp = (cnt + 63) & ~63;

    // ---- fill V3L: this w's 16 rows = 2880 floats = 720 f4, straight copy
    {
        const float4* src = (const float4*)(Sg + (size_t)(e * C_ + c) * SRS
                                            + (size_t)w * 16 * RSTR);
        float4* dst = (float4*)V3L;
        #pragma unroll
        for (int r = 0; r < 2; ++r) dst[t + 256 * r] = src[t + 256 * r];
        if (t < 208) dst[512 + t] = src[512 + t];
    }
    const float v1x = U1[w * 16 + xx] * w1[e * C_ + c];
    __syncthreads();

    const float* v3p = &V3L[xx * RSTR];
    const int SO[16] = SEG_OFF_INIT;

    // ---- chunk loop: 64 rows per chunk, 4 per thread ----
    #pragma clang loop unroll(disable)
    for (int base = 0; base < cntp; base += 64) {
        __syncthreads();   // anti-LICM liveness pin (see header note)

        const int slot = base + bs * 4;
        int bidx[4];
        #pragma unroll
        for (int r = 0; r < 4; ++r) bidx[r] = list_g[e * B_ + slot + r];

        float xm[4][19];   // x row + 3 zero pads (segment tails index up to 18)
        float xo[4];
        #pragma unroll
        for (int r = 0; r < 4; ++r) {
            const float* xb = x + ((size_t)bidx[r] * C_ + c) * ELL;
            #pragma unroll
            for (int i4 = 0; i4 < 4; ++i4) {
                float4 a = ((const float4*)xb)[i4];
                xm[r][4 * i4 + 0] = a.x; xm[r][4 * i4 + 1] = a.y;
                xm[r][4 * i4 + 2] = a.z; xm[r][4 * i4 + 3] = a.w;
            }
            xm[r][16] = 0.f; xm[r][17] = 0.f; xm[r][18] = 0.f;
            xo[r] = xb[xx];   // own-x element (L1 hit; no dynamic reg index)
        }

        float t2[4] = {0.f, 0.f, 0.f, 0.f};
        #pragma unroll
        for (int v = 0; v < 16; ++v) {
            const int off = SO[v];
            const int nf4 = (v == 0) ? 5 : (v < 5) ? 4 : (v < 9) ? 3 : (v < 13) ? 2 : 1;
            float inner[4];
            {   // first f4: [lin, Q_vv, Q_v,v+1, Q_v,v+2]
                float4 u = *(const float4*)(v3p + off);
                #pragma unroll
                for (int r = 0; r < 4; ++r)
                    inner[r] = u.x + u.y * xm[r][v]
                             + u.z * xm[r][v + 1] + u.w * xm[r][v + 2];
            }
            #pragma unroll
            for (int q = 1; q < nf4; ++q) {
                float4 u = *(const float4*)(v3p + off + 4 * q);
                #pragma unroll
                for (int r = 0; r < 4; ++r) {
                    inner[r] += u.x * xm[r][v + 4 * q - 1];
                    inner[r] += u.y * xm[r][v + 4 * q + 0];
                    inner[r] += u.z * xm[r][v + 4 * q + 1];
                    inner[r] += u.w * xm[r][v + 4 * q + 2];
                }
            }
            #pragma unroll
            for (int r = 0; r < 4; ++r) t2[r] += xm[r][v] * inner[r];
        }

        // out[b,c,w] = sum_xx (t2 + v1[xx]) * x[xx]  -- width-16 butterfly
        float cv[4];
        #pragma unroll
        for (int r = 0; r < 4; ++r) cv[r] = (t2[r] + v1x) * xo[r];
        #pragma unroll
        for (int m = 1; m < 16; m <<= 1) {
            #pragma unroll
            for (int r = 0; r < 4; ++r) cv[r] += __shfl_xor(cv[r], m, 16);
        }
        if (xx == 0) {
            #pragma unroll
            for (int r = 0; r < 4; ++r)
                if (slot + r < cnt)
                    out[(size_t)bidx[r] * (C_ * EQ) + c * EQ + w] = cv[r];
        }
    }
}

// ---------------------------------------------------------------------------
extern "C" void kernel_launch(void* const* d_in, const int* in_sizes, int n_in,
                              void* d_out, int out_size, void* d_ws, size_t ws_size,
                              hipStream_t stream) {
    const float* x    = (const float*)d_in[0];
    const float* y    = (const float*)d_in[1];
    const float* U3   = (const float*)d_in[2];
    const float* U2   = (const float*)d_in[3];
    const float* U1   = (const float*)d_in[4];
    const float* wmax = (const float*)d_in[5];
    const float* w2   = (const float*)d_in[6];
    const float* w1   = (const float*)d_in[7];
    float* out = (float*)d_out;
    char*  ws  = (char*)d_ws;

    int*   cnt_g  = (int*)(ws + WS_CNT);
    int*   list_g = (int*)(ws + WS_LIST);
    float* coefG  = (float*)(ws + WS_COEF);
    float* Sg     = (float*)(ws + WS_S);
    (void)ws_size;   // needs ~46.3 MB; harness ws confirmed >= 66 MB (r1-r9)

    k_coef<<<49, 256, 0, stream>>>(U3, U2, y, coefG, cnt_g, list_g);
    k_s<<<dim3(48, E_), 256, 0, stream>>>(coefG, wmax, w2, Sg);
    k_main<<<dim3(C_ * EQ, E_), 256, 0, stream>>>(x, Sg, U1, w1, cnt_g, list_g, out);
}

// Round 17
// 145.572 us; speedup vs baseline: 1.2888x; 1.0641x over previous
//
#include <hip/hip_runtime.h>

// Problem constants
#define B_    1024
#define C_    128
#define ELL   16
#define EQ    3
#define E_    10
#define P3    23
#define P2    5
#define NSEG  176            // padded segment row: 16 f4-aligned v-segments
#define RSTR  180            // V3L row stride (180%32=20 -> 2-way bank aliasing, free)
#define KD    28             // folded weight depth: 23 (wmax) + 5 (w2)

// ws layout (bytes)
#define WS_CNT   0
#define WS_LIST  64
#define WS_COEFT 65536       // coefT[48][28][176] = 946 KB (e-independent, L2/L3-hot)

// segment offsets: v-th segment holds [lin_v, Q_vv, Q_v,v+1, .., Q_v,15, pad0s]
// lengths (real) 17-v, padded to x4: {20,16,16,16,16,12,12,12,12,8,8,8,8,4,4,4}
#define SEG_OFF_INIT {0,20,36,52,68,84,96,108,120,132,140,148,156,164,168,172}

// ---------------------------------------------------------------------------
// Bucketing: bucket batch indices by element, pad each bucket to x64 by
// replicating the last real index (k_main then needs no load guards).
__device__ void do_lists(const float* __restrict__ y, int* __restrict__ cnt_g,
                         int* __restrict__ list_g, int t) {
    __shared__ int lcnt[E_];
    if (t < E_) lcnt[t] = 0;
    __syncthreads();
    for (int r = 0; r < 4; ++r) {
        int b = t + 256 * r;
        int e = 0;
        #pragma unroll
        for (int j = 1; j < E_; ++j)
            if (y[b * E_ + j] > 0.5f) e = j;
        int slot = atomicAdd(&lcnt[e], 1);
        list_g[e * B_ + slot] = b;
    }
    __syncthreads();
    if (t < E_) {
        int c0 = lcnt[t];
        cnt_g[t] = c0;
        int last = (c0 > 0) ? list_g[t * B_ + c0 - 1] : 0;
        int cp = (c0 + 63) & ~63;
        if (cp > B_) cp = B_;
        for (int s2 = c0; s2 < cp; ++s2) list_g[t * B_ + s2] = last;
    }
}

// ---------------------------------------------------------------------------
// k_coefT: symmetrized coefficient rows (algebra verified r14-r16), stored
// TRANSPOSED: coefT[(j*28 + k)*176 + idx], so k_main's fill reads are
// lane-contiguous (idx = lane).
//   idx<136 slots (v,l>0): coef[k<23] = U3[j,v,i,k] + (i!=v)*U3[j,i,v,k], i=v+l-1
//   l==0 slots:            coef[23+q] = U2[j,v,q]; pad slots zero.
// grid 49: blocks 0..47 -> j; block 48 does bucketing.
__global__ __launch_bounds__(256, 2) void k_coefT(const float* __restrict__ U3,
                                                  const float* __restrict__ U2,
                                                  const float* __restrict__ y,
                                                  float* __restrict__ coefT,
                                                  int* __restrict__ cnt_g,
                                                  int* __restrict__ list_g) {
    const int t = threadIdx.x;
    if (blockIdx.x == 48) { do_lists(y, cnt_g, list_g, t); return; }
    __shared__ __align__(16) float U3L[ELL * ELL * P3];  // 23,552 B
    const int j = blockIdx.x;

    {   // stage U3[j] (1472 f4), fully coalesced
        const float4* src4 = (const float4*)(U3 + (size_t)j * (ELL * ELL * P3));
        float4* dst4 = (float4*)U3L;
        for (int f = t; f < 1472; f += 256) dst4[f] = src4[f];
    }
    __syncthreads();
    if (t >= NSEG) return;

    const int SO[16] = SEG_OFF_INIT;
    int v = 0;
    #pragma unroll
    for (int s = 1; s < 16; ++s) v += (t >= SO[s]) ? 1 : 0;
    const int l    = t - SO[v];
    const int real = 17 - v;

    float outk[KD];
    #pragma unroll
    for (int k = 0; k < KD; ++k) outk[k] = 0.f;

    if (l == 0) {
        #pragma unroll
        for (int q = 0; q < P2; ++q)
            outk[23 + q] = U2[(size_t)j * (ELL * P2) + v * P2 + q];
    } else if (l < real) {
        int i = v + l - 1;
        const float* pa = &U3L[(v * ELL + i) * P3];
        const float* pb = &U3L[(i * ELL + v) * P3];
        if (i != v) {
            #pragma unroll
            for (int k = 0; k < P3; ++k) outk[k] = pa[k] + pb[k];
        } else {
            #pragma unroll
            for (int k = 0; k < P3; ++k) outk[k] = pa[k];
        }
    }
    // transposed store: 28 coalesced 704-B stores (lanes 0..175 contiguous)
    float* cb = coefT + (size_t)j * KD * NSEG + t;
    #pragma unroll
    for (int k = 0; k < KD; ++k) cb[(size_t)k * NSEG] = outk[k];
}

// ---------------------------------------------------------------------------
// k_main: r12's verified hot loop; fill phase now COMPUTES the S rows from
// coefT (L2/L3-hot, e-independent) instead of reading a 44 MB Sg from HBM --
// k_s and the Sg round-trip are deleted. wl[28] is block-uniform (scalar
// loads); fill = 11 x (28 coalesced b32 loads + 28 FMA + 1 LDS write)/thread.
// grid (C_*EQ, E_), 256 threads; bx = c*3+w. xx = t&15 (row), bs = t>>4;
// 4 batch rows/thread -> chunk = 64 rows.
// CRITICAL: __syncthreads() per chunk + unroll(disable) -- without them LICM
// hoists loop-invariant LDS reads -> VGPR blowup -> scratch spill (r5/r6).
// (r13: 8 rows/thread -> occupancy 19%, regress. r14: strided Sg -> gather,
//  +34 us. r15: lane=c store scatter -> WRITE 116 MB, 57 us. r16: 3-kernel
//  chain + Sg round-trip -> 155 total vs r12's 139.)
__global__ __launch_bounds__(256, 2) void k_main(
    const float* __restrict__ x, const float* __restrict__ coefT,
    const float* __restrict__ wmax, const float* __restrict__ w2,
    const float* __restrict__ U1, const float* __restrict__ w1,
    const int* __restrict__ cnt_g, const int* __restrict__ list_g,
    float* __restrict__ out) {

    __shared__ __align__(16) float V3L[16 * RSTR];   // 11,520 B

    const int t  = threadIdx.x;
    const int bx = blockIdx.x;
    const int w  = bx % 3, c = bx / 3;
    const int e  = blockIdx.y;
    const int xx = t & 15, bs = t >> 4;
    const int cnt  = cnt_g[e];
    const int cntp = (cnt + 63) & ~63;

    // ---- folded weight vector (block-uniform -> scalar loads) ----
    float wl[KD];
    #pragma unroll
    for (int k = 0; k < P3; ++k) wl[k] = wmax[(e * P3 + k) * C_ + c];
    #pragma unroll
    for (int q = 0; q < P2; ++q) wl[23 + q] = w2[(e * P2 + q) * C_ + c];

    // ---- fill V3L by computing S[row][idx] = sum_k coefT[j][k][idx]*wl[k]
    // 16 rows x 176 idx = 2816 = 11 x 256 outputs; lanes mostly contiguous.
    {
        const float* cwb = coefT + (size_t)(w * 16) * KD * NSEG;
        #pragma clang loop unroll(disable)
        for (int s = 0; s < 11; ++s) {
            const int f   = t + 256 * s;
            const int row = f / NSEG, idx = f - row * NSEG;
            const float* cp = cwb + (size_t)row * KD * NSEG + idx;
            float a = 0.f;
            #pragma unroll
            for (int k = 0; k < KD; ++k) a += cp[(size_t)k * NSEG] * wl[k];
            V3L[row * RSTR + idx] = a;
        }
    }
    const float v1x = U1[w * 16 + xx] * w1[e * C_ + c];
    __syncthreads();

    const float* v3p = &V3L[xx * RSTR];
    const int SO[16] = SEG_OFF_INIT;

    // ---- chunk loop: 64 rows per chunk, 4 per thread ----
    #pragma clang loop unroll(disable)
    for (int base = 0; base < cntp; base += 64) {
        __syncthreads();   // anti-LICM liveness pin (see header note)

        const int slot = base + bs * 4;
        int bidx[4];
        #pragma unroll
        for (int r = 0; r < 4; ++r) bidx[r] = list_g[e * B_ + slot + r];

        float xm[4][19];   // x row + 3 zero pads (segment tails index up to 18)
        float xo[4];
        #pragma unroll
        for (int r = 0; r < 4; ++r) {
            const float* xb = x + ((size_t)bidx[r] * C_ + c) * ELL;
            #pragma unroll
            for (int i4 = 0; i4 < 4; ++i4) {
                float4 a = ((const float4*)xb)[i4];
                xm[r][4 * i4 + 0] = a.x; xm[r][4 * i4 + 1] = a.y;
                xm[r][4 * i4 + 2] = a.z; xm[r][4 * i4 + 3] = a.w;
            }
            xm[r][16] = 0.f; xm[r][17] = 0.f; xm[r][18] = 0.f;
            xo[r] = xb[xx];   // own-x element (L1 hit; no dynamic reg index)
        }

        float t2[4] = {0.f, 0.f, 0.f, 0.f};
        #pragma unroll
        for (int v = 0; v < 16; ++v) {
            const int off = SO[v];
            const int nf4 = (v == 0) ? 5 : (v < 5) ? 4 : (v < 9) ? 3 : (v < 13) ? 2 : 1;
            float inner[4];
            {   // first f4: [lin, Q_vv, Q_v,v+1, Q_v,v+2]
                float4 u = *(const float4*)(v3p + off);
                #pragma unroll
                for (int r = 0; r < 4; ++r)
                    inner[r] = u.x + u.y * xm[r][v]
                             + u.z * xm[r][v + 1] + u.w * xm[r][v + 2];
            }
            #pragma unroll
            for (int q = 1; q < nf4; ++q) {
                float4 u = *(const float4*)(v3p + off + 4 * q);
                #pragma unroll
                for (int r = 0; r < 4; ++r) {
                    inner[r] += u.x * xm[r][v + 4 * q - 1];
                    inner[r] += u.y * xm[r][v + 4 * q + 0];
                    inner[r] += u.z * xm[r][v + 4 * q + 1];
                    inner[r] += u.w * xm[r][v + 4 * q + 2];
                }
            }
            #pragma unroll
            for (int r = 0; r < 4; ++r) t2[r] += xm[r][v] * inner[r];
        }

        // out[b,c,w] = sum_xx (t2 + v1[xx]) * x[xx]  -- width-16 butterfly
        float cv[4];
        #pragma unroll
        for (int r = 0; r < 4; ++r) cv[r] = (t2[r] + v1x) * xo[r];
        #pragma unroll
        for (int m = 1; m < 16; m <<= 1) {
            #pragma unroll
            for (int r = 0; r < 4; ++r) cv[r] += __shfl_xor(cv[r], m, 16);
        }
        if (xx == 0) {
            #pragma unroll
            for (int r = 0; r < 4; ++r)
                if (slot + r < cnt)
                    out[(size_t)bidx[r] * (C_ * EQ) + c * EQ + w] = cv[r];
        }
    }
}

// ---------------------------------------------------------------------------
extern "C" void kernel_launch(void* const* d_in, const int* in_sizes, int n_in,
                              void* d_out, int out_size, void* d_ws, size_t ws_size,
                              hipStream_t stream) {
    const float* x    = (const float*)d_in[0];
    const float* y    = (const float*)d_in[1];
    const float* U3   = (const float*)d_in[2];
    const float* U2   = (const float*)d_in[3];
    const float* U1   = (const float*)d_in[4];
    const float* wmax = (const float*)d_in[5];
    const float* w2   = (const float*)d_in[6];
    const float* w1   = (const float*)d_in[7];
    float* out = (float*)d_out;
    char*  ws  = (char*)d_ws;

    int*   cnt_g  = (int*)(ws + WS_CNT);
    int*   list_g = (int*)(ws + WS_LIST);
    float* coefT  = (float*)(ws + WS_COEFT);
    (void)ws_size;   // needs ~1.0 MB only now

    k_coefT<<<49, 256, 0, stream>>>(U3, U2, y, coefT, cnt_g, list_g);
    k_main<<<dim3(C_ * EQ, E_), 256, 0, stream>>>(x, coefT, wmax, w2, U1, w1,
                                                  cnt_g, list_g, out);
}